// Round 2
// baseline (356.174 us; speedup 1.0000x reference)
//
#include <hip/hip_runtime.h>
#include <math.h>

#define BATCH 16
#define CH    64
#define HH    128
#define WW    128
#define PLANE (HH*WW)              // 16384
#define OUT0  (BATCH*3*CH*PLANE)   // 50331648

// K3 per-plane LDS: 138 padded rows x 144 padded cols
#define LROW  144
#define LROWS 138

// ws float layout:
//  [0,1024)      T  (logit threshold per (b,c))
//  [1024,2048)   ps
//  [2048,3072)   S
//  [3072,4096)   Sw
//  [4096,5120)   Sh
//  [5120,6144)   Scol
//  [6144,7168)   Srow
//  [7168,7232)   cw  per channel (128 * w_width_sh * w_bbx)
//  [7232,7296)   chs per channel (128 * w_height_sh * w_bbx)
//  [8192, +256K) mw map  (16 x 16384)
//  [270336,...)  mh map
//  [532480,...)  msc map
#define CW_OFF  7168
#define CHS_OFF 7232
#define MW_OFF  8192
#define MH_OFF  270336
#define MS_OFF  532480

// Shared conv core. base points at padded (first_tap_row, window_start_col);
// row stride 144. Reads rows base..base+10 (vert taps, col offset +8) and the
// 20-float horizontal window on row base+5. MUST be bitwise-deterministic:
// explicit fmaf, fixed order — used by BOTH k_cmax and k_write so that the
// (v == max) mask is self-consistent.
__device__ __forceinline__ void conv4(const float* __restrict__ base,
                                      const float* __restrict__ wk,
                                      const float* __restrict__ hk,
                                      float cw, float chs, float T,
                                      float4& w4, float4& h4, float4& s4) {
    float4 vx;
    float hx = 0.f, hy = 0.f, hz = 0.f, hw = 0.f;
#pragma unroll
    for (int k = 0; k < 11; k++) {
        float4 v = *(const float4*)(base + k * 144 + 8);
        if (k == 5) vx = v;
        hx = fmaf(v.x, hk[k], hx);
        hy = fmaf(v.y, hk[k], hy);
        hz = fmaf(v.z, hk[k], hz);
        hw = fmaf(v.w, hk[k], hw);
    }
    float wbuf[20];
    {
        float4 a0 = *(const float4*)(base + 5 * 144 + 0);
        float4 a1 = *(const float4*)(base + 5 * 144 + 4);
        float4 a3 = *(const float4*)(base + 5 * 144 + 12);
        float4 a4 = *(const float4*)(base + 5 * 144 + 16);
        wbuf[0] = a0.x;  wbuf[1] = a0.y;  wbuf[2] = a0.z;  wbuf[3] = a0.w;
        wbuf[4] = a1.x;  wbuf[5] = a1.y;  wbuf[6] = a1.z;  wbuf[7] = a1.w;
        wbuf[8] = vx.x;  wbuf[9] = vx.y;  wbuf[10] = vx.z; wbuf[11] = vx.w;
        wbuf[12] = a3.x; wbuf[13] = a3.y; wbuf[14] = a3.z; wbuf[15] = a3.w;
        wbuf[16] = a4.x; wbuf[17] = a4.y; wbuf[18] = a4.z; wbuf[19] = a4.w;
    }
    float wo[4];
#pragma unroll
    for (int j = 0; j < 4; j++) {
        float acc = 0.f;
#pragma unroll
        for (int k = 0; k < 11; k++) acc = fmaf(wbuf[j + 3 + k], wk[k], acc);
        wo[j] = acc * cw;
    }
    w4.x = wo[0]; w4.y = wo[1]; w4.z = wo[2]; w4.w = wo[3];
    h4.x = hx * chs; h4.y = hy * chs; h4.z = hz * chs; h4.w = hw * chs;
    s4.x = (vx.x > T) ? vx.x : 0.f;
    s4.y = (vx.y > T) ? vx.y : 0.f;
    s4.z = (vx.z > T) ? vx.z : 0.f;
    s4.w = (vx.w > T) ? vx.w : 0.f;
}

// ---------------- K1: per-(b,c) max of x -> T, ps ; fold scales ----------------
__global__ __launch_bounds__(256) void k_max(const float* __restrict__ x,
                                             const float* __restrict__ w_bbx,
                                             const float* __restrict__ w_width_sh,
                                             const float* __restrict__ w_height_sh,
                                             float* __restrict__ ws) {
    int bid = blockIdx.x;                    // b*64+c
    const float4* xp = (const float4*)(x + (size_t)bid * PLANE);
    int tid = threadIdx.x;
    float m = -INFINITY;
#pragma unroll
    for (int i = 0; i < 16; i++) {
        float4 v = xp[i * 256 + tid];
        m = fmaxf(m, fmaxf(fmaxf(v.x, v.y), fmaxf(v.z, v.w)));
    }
#pragma unroll
    for (int off = 32; off; off >>= 1) m = fmaxf(m, __shfl_xor(m, off, 64));
    __shared__ float sm[4];
    int wid = tid >> 6, lane = tid & 63;
    if (lane == 0) sm[wid] = m;
    __syncthreads();
    if (tid == 0) {
        float mm = fmaxf(fmaxf(sm[0], sm[1]), fmaxf(sm[2], sm[3]));
        float ps = 1.0f / (1.0f + expf(-mm));
        float M = ps - 0.01f;
        float T = (M > 0.0f) ? logf(M / (1.0f - M)) : -INFINITY;
        ws[bid] = T;
        ws[1024 + bid] = ps;
    }
    if (bid < 64 && tid == 1) {
        float cb = w_bbx[bid];
        ws[CW_OFF + bid]  = 128.0f * w_width_sh[bid] * cb;
        ws[CHS_OFF + bid] = 128.0f * w_height_sh[bid] * cb;
    }
}

// ------- K2: per-pixel channel-max maps (mw, mh, msc), no field writes -------
__global__ __launch_bounds__(256) void k_cmax(const float* __restrict__ x,
                                              const float* __restrict__ w_width,
                                              const float* __restrict__ w_height,
                                              float* __restrict__ ws) {
    // block = (b, band of 8 rows); all 64 channels in chunks of 4
    __shared__ float4 xs4[4 * 18 * 36];      // 4ch x 18rows x 144cols floats
    float* xs = (float*)xs4;
    int bid = blockIdx.x;
    int b = bid >> 4;
    int r0 = (bid & 15) * 8;
    int tid = threadIdx.x;

    // zero once; invalid rows / col halos never rewritten -> stay zero
    for (int i = tid; i < 4 * 18 * 36; i += 256)
        xs4[i] = make_float4(0.f, 0.f, 0.f, 0.f);

    int lr_o = tid >> 5;             // 0..7  output row within band
    int c0 = (tid & 31) << 2;        // 0,4,...,124

    float4 mw = make_float4(-INFINITY, -INFINITY, -INFINITY, -INFINITY);
    float4 mh = mw, ms = mw;

    for (int ch0 = 0; ch0 < 64; ch0 += 4) {
        __syncthreads();             // compute of prev chunk done (and zero-fill)
        // stage 4ch x 18rows(valid subset) x 128cols
        for (int j = tid; j < 4 * 576; j += 256) {
            int i = j / 576;
            int rem = j - i * 576;
            int lr = rem >> 5;
            int c4 = rem & 31;
            int gr = r0 - 5 + lr;
            if (gr >= 0 && gr < 128) {
                float4 v = *(const float4*)(x +
                    ((size_t)((b * 64 + ch0 + i) * 128 + gr)) * 128 + c4 * 4);
                *(float4*)(xs + (i * 18 + lr) * 144 + 8 + c4 * 4) = v;
            }
        }
        __syncthreads();
#pragma unroll
        for (int i = 0; i < 4; i++) {
            int c = ch0 + i;
            float T   = ws[b * 64 + c];
            float cw  = ws[CW_OFF + c];
            float chs = ws[CHS_OFF + c];
            float wk[11], hk[11];
#pragma unroll
            for (int k = 0; k < 11; k++) {
                wk[k] = w_width[c * 11 + k];
                hk[k] = w_height[c * 11 + k];
            }
            float4 w4, h4, s4;
            conv4(xs + (i * 18 + lr_o) * 144 + c0, wk, hk, cw, chs, T, w4, h4, s4);
            mw.x = fmaxf(mw.x, w4.x); mw.y = fmaxf(mw.y, w4.y);
            mw.z = fmaxf(mw.z, w4.z); mw.w = fmaxf(mw.w, w4.w);
            mh.x = fmaxf(mh.x, h4.x); mh.y = fmaxf(mh.y, h4.y);
            mh.z = fmaxf(mh.z, h4.z); mh.w = fmaxf(mh.w, h4.w);
            ms.x = fmaxf(ms.x, s4.x); ms.y = fmaxf(ms.y, s4.y);
            ms.z = fmaxf(ms.z, s4.z); ms.w = fmaxf(ms.w, s4.w);
        }
    }
    int p = b * PLANE + (r0 + lr_o) * 128 + c0;
    *(float4*)(ws + MW_OFF + p) = mw;
    *(float4*)(ws + MH_OFF + p) = mh;
    *(float4*)(ws + MS_OFF + p) = ms;
}

// -------- K3: recompute fields, mask vs maps, write once; plane sums --------
__global__ __launch_bounds__(256) void k_write(
    const float* __restrict__ x,
    const float* __restrict__ w_width, const float* __restrict__ w_height,
    float* __restrict__ ws, float* __restrict__ out) {
    __shared__ float xs[LROWS * LROW];
    __shared__ float red[4 * 5];
    int bid = blockIdx.x;                  // b*64 + c
    int b = bid >> 6, c = bid & 63;
    int tid = threadIdx.x;

    for (int i = tid; i < LROWS * LROW; i += 256) xs[i] = 0.0f;
    __syncthreads();
    const float* xp = x + (size_t)bid * PLANE;
#pragma unroll
    for (int i = 0; i < 16; i++) {
        int idx = i * 256 + tid;
        int p = idx * 4;
        int y = p >> 7, xc = p & 127;
        float4 v = ((const float4*)xp)[idx];
        *(float4*)&xs[(y + 5) * LROW + xc + 8] = v;
    }
    float wk[11], hk[11];
#pragma unroll
    for (int k = 0; k < 11; k++) {
        wk[k] = w_width[c * 11 + k];
        hk[k] = w_height[c * 11 + k];
    }
    float T   = ws[bid];
    float cw  = ws[CW_OFF + c];
    float chs = ws[CHS_OFF + c];
    __syncthreads();

    float S = 0.f, Sw = 0.f, Sh = 0.f, Scol = 0.f, Srow = 0.f;
    float* outS = out + (size_t)(b * 192 + c) * PLANE;
    float* outW = out + (size_t)(b * 192 + 64 + c) * PLANE;
    float* outH = out + (size_t)(b * 192 + 128 + c) * PLANE;
    const float* mwp = ws + MW_OFF + b * PLANE;
    const float* mhp = ws + MH_OFF + b * PLANE;
    const float* msp = ws + MS_OFF + b * PLANE;

    for (int g = 0; g < 16; g++) {
        int idx = g * 256 + tid;
        int p = idx * 4;
        int y = p >> 7, xc = p & 127;
        float4 w4, h4, s4;
        conv4(xs + y * LROW + xc, wk, hk, cw, chs, T, w4, h4, s4);

        // plane sums use UNMASKED values
        float s4sum = s4.x + s4.y + s4.z + s4.w;
        S += s4sum;
        Srow += (float)y * s4sum;
        Sw = fmaf(w4.x, s4.x, Sw); Sw = fmaf(w4.y, s4.y, Sw);
        Sw = fmaf(w4.z, s4.z, Sw); Sw = fmaf(w4.w, s4.w, Sw);
        Sh = fmaf(h4.x, s4.x, Sh); Sh = fmaf(h4.y, s4.y, Sh);
        Sh = fmaf(h4.z, s4.z, Sh); Sh = fmaf(h4.w, s4.w, Sh);
        Scol = fmaf((float)(xc + 0), s4.x, Scol);
        Scol = fmaf((float)(xc + 1), s4.y, Scol);
        Scol = fmaf((float)(xc + 2), s4.z, Scol);
        Scol = fmaf((float)(xc + 3), s4.w, Scol);

        float4 mw = *(const float4*)(mwp + p);
        float4 mh = *(const float4*)(mhp + p);
        float4 ms = *(const float4*)(msp + p);
        float4 o;
        o.x = (s4.x == ms.x) ? s4.x : 0.f;
        o.y = (s4.y == ms.y) ? s4.y : 0.f;
        o.z = (s4.z == ms.z) ? s4.z : 0.f;
        o.w = (s4.w == ms.w) ? s4.w : 0.f;
        ((float4*)outS)[idx] = o;
        o.x = (w4.x == mw.x) ? w4.x : 0.f;
        o.y = (w4.y == mw.y) ? w4.y : 0.f;
        o.z = (w4.z == mw.z) ? w4.z : 0.f;
        o.w = (w4.w == mw.w) ? w4.w : 0.f;
        ((float4*)outW)[idx] = o;
        o.x = (h4.x == mh.x) ? h4.x : 0.f;
        o.y = (h4.y == mh.y) ? h4.y : 0.f;
        o.z = (h4.z == mh.z) ? h4.z : 0.f;
        o.w = (h4.w == mh.w) ? h4.w : 0.f;
        ((float4*)outH)[idx] = o;
    }
#pragma unroll
    for (int off = 32; off; off >>= 1) {
        S    += __shfl_xor(S, off, 64);
        Sw   += __shfl_xor(Sw, off, 64);
        Sh   += __shfl_xor(Sh, off, 64);
        Scol += __shfl_xor(Scol, off, 64);
        Srow += __shfl_xor(Srow, off, 64);
    }
    int wid = tid >> 6, lane = tid & 63;
    if (lane == 0) {
        red[wid * 5 + 0] = S;   red[wid * 5 + 1] = Sw;
        red[wid * 5 + 2] = Sh;  red[wid * 5 + 3] = Scol;
        red[wid * 5 + 4] = Srow;
    }
    __syncthreads();
    if (tid == 0) {
        float a0 = 0, a1 = 0, a2 = 0, a3 = 0, a4 = 0;
#pragma unroll
        for (int w2 = 0; w2 < 4; w2++) {
            a0 += red[w2 * 5 + 0]; a1 += red[w2 * 5 + 1];
            a2 += red[w2 * 5 + 2]; a3 += red[w2 * 5 + 3];
            a4 += red[w2 * 5 + 4];
        }
        ws[2048 + bid] = a0;
        ws[3072 + bid] = a1;
        ws[4096 + bid] = a2;
        ws[5120 + bid] = a3;
        ws[6144 + bid] = a4;
    }
}

// ---------------- K4: bbox rows ----------------
__global__ __launch_bounds__(256) void k_bbox(const float* __restrict__ ws,
                                              float* __restrict__ out) {
    int idx = blockIdx.x * 256 + threadIdx.x;
    if (idx >= 1024) return;
    int b = idx >> 6;
    float S    = ws[2048 + idx];
    float Sw   = ws[3072 + idx];
    float Sh   = ws[4096 + idx];
    float Scol = ws[5120 + idx];
    float Srow = ws[6144 + idx];
    float ps   = ws[1024 + idx];
    float inv = 1.0f / S;
    float wsv = Sw * inv, hsv = Sh * inv;
    float x1 = Scol * inv - 0.5f * wsv;
    float y1 = Srow * inv - 0.5f * hsv;
    float* o = out + OUT0 + (size_t)idx * 6;
    o[0] = (float)b;
    o[1] = x1;
    o[2] = y1;
    o[3] = x1 + wsv;
    o[4] = y1 + hsv;
    o[5] = ps;
}

extern "C" void kernel_launch(void* const* d_in, const int* in_sizes, int n_in,
                              void* d_out, int out_size, void* d_ws, size_t ws_size,
                              hipStream_t stream) {
    const float* x          = (const float*)d_in[0];
    const float* w_bbx      = (const float*)d_in[1];
    const float* w_width    = (const float*)d_in[2];
    const float* w_width_sh = (const float*)d_in[3];
    const float* w_height   = (const float*)d_in[4];
    const float* w_height_sh= (const float*)d_in[5];
    float* out = (float*)d_out;
    float* ws  = (float*)d_ws;

    k_max<<<dim3(1024), dim3(256), 0, stream>>>(x, w_bbx, w_width_sh, w_height_sh, ws);
    k_cmax<<<dim3(256), dim3(256), 0, stream>>>(x, w_width, w_height, ws);
    k_write<<<dim3(1024), dim3(256), 0, stream>>>(x, w_width, w_height, ws, out);
    k_bbox<<<dim3(4), dim3(256), 0, stream>>>(ws, out);
}

// Round 3
// 318.131 us; speedup vs baseline: 1.1196x; 1.1196x over previous
//
#include <hip/hip_runtime.h>
#include <math.h>

#define BATCH 16
#define CH    64
#define HH    128
#define WW    128
#define PLANE (HH*WW)              // 16384
#define OUT0  (BATCH*3*CH*PLANE)   // 50331648
#define BP    (BATCH*PLANE)        // 262144 floats per map

// ws float layout:
//  [0,1024)        T (logit threshold per (b,c))
//  [1024,2048)     ps
//  [2048,12288)    sums [half][5][1024]
//  [12288,12352)   cw  per channel
//  [12352,12416)   chs per channel
//  [16384, ...)    partial maps [cgroup(4)][field(3)][BP]
//  [3163136, ...)  final maps   [field(3)][BP]
#define T_OFF   0
#define PS_OFF  1024
#define SUM_OFF 2048
#define CW_OFF  12288
#define CHS_OFF 12352
#define MAP_OFF 16384
#define FMAP_OFF 3163136

// Shared conv core — MUST be bitwise-deterministic (explicit fmaf, fixed
// order); used by BOTH k_cmax and k_write so (v == max) masks are consistent.
// base points at padded (first_tap_row, window_start_col); row stride 144.
__device__ __forceinline__ void conv4(const float* __restrict__ base,
                                      const float* __restrict__ wk,
                                      const float* __restrict__ hk,
                                      float cw, float chs, float T,
                                      float4& w4, float4& h4, float4& s4) {
    float4 vx;
    float hx = 0.f, hy = 0.f, hz = 0.f, hw = 0.f;
#pragma unroll
    for (int k = 0; k < 11; k++) {
        float4 v = *(const float4*)(base + k * 144 + 8);
        if (k == 5) vx = v;
        hx = fmaf(v.x, hk[k], hx);
        hy = fmaf(v.y, hk[k], hy);
        hz = fmaf(v.z, hk[k], hz);
        hw = fmaf(v.w, hk[k], hw);
    }
    float wbuf[20];
    {
        float4 a0 = *(const float4*)(base + 5 * 144 + 0);
        float4 a1 = *(const float4*)(base + 5 * 144 + 4);
        float4 a3 = *(const float4*)(base + 5 * 144 + 12);
        float4 a4 = *(const float4*)(base + 5 * 144 + 16);
        wbuf[0] = a0.x;  wbuf[1] = a0.y;  wbuf[2] = a0.z;  wbuf[3] = a0.w;
        wbuf[4] = a1.x;  wbuf[5] = a1.y;  wbuf[6] = a1.z;  wbuf[7] = a1.w;
        wbuf[8] = vx.x;  wbuf[9] = vx.y;  wbuf[10] = vx.z; wbuf[11] = vx.w;
        wbuf[12] = a3.x; wbuf[13] = a3.y; wbuf[14] = a3.z; wbuf[15] = a3.w;
        wbuf[16] = a4.x; wbuf[17] = a4.y; wbuf[18] = a4.z; wbuf[19] = a4.w;
    }
    float wo[4];
#pragma unroll
    for (int j = 0; j < 4; j++) {
        float acc = 0.f;
#pragma unroll
        for (int k = 0; k < 11; k++) acc = fmaf(wbuf[j + 3 + k], wk[k], acc);
        wo[j] = acc * cw;
    }
    w4.x = wo[0]; w4.y = wo[1]; w4.z = wo[2]; w4.w = wo[3];
    h4.x = hx * chs; h4.y = hy * chs; h4.z = hz * chs; h4.w = hw * chs;
    s4.x = (vx.x > T) ? vx.x : 0.f;
    s4.y = (vx.y > T) ? vx.y : 0.f;
    s4.z = (vx.z > T) ? vx.z : 0.f;
    s4.w = (vx.w > T) ? vx.w : 0.f;
}

// ---------------- K1: per-(b,c) max of x -> T, ps ; fold scales ----------------
__global__ __launch_bounds__(256) void k_max(const float* __restrict__ x,
                                             const float* __restrict__ w_bbx,
                                             const float* __restrict__ w_width_sh,
                                             const float* __restrict__ w_height_sh,
                                             float* __restrict__ ws) {
    int bid = blockIdx.x;                    // b*64+c
    const float4* xp = (const float4*)(x + (size_t)bid * PLANE);
    int tid = threadIdx.x;
    float m = -INFINITY;
#pragma unroll
    for (int i = 0; i < 16; i++) {
        float4 v = xp[i * 256 + tid];
        m = fmaxf(m, fmaxf(fmaxf(v.x, v.y), fmaxf(v.z, v.w)));
    }
#pragma unroll
    for (int off = 32; off; off >>= 1) m = fmaxf(m, __shfl_xor(m, off, 64));
    __shared__ float sm[4];
    int wid = tid >> 6, lane = tid & 63;
    if (lane == 0) sm[wid] = m;
    __syncthreads();
    if (tid == 0) {
        float mm = fmaxf(fmaxf(sm[0], sm[1]), fmaxf(sm[2], sm[3]));
        float ps = 1.0f / (1.0f + expf(-mm));
        float M = ps - 0.01f;
        float T = (M > 0.0f) ? logf(M / (1.0f - M)) : -INFINITY;
        ws[T_OFF + bid] = T;
        ws[PS_OFF + bid] = ps;
    }
    if (bid < 64 && tid == 1) {
        float cb = w_bbx[bid];
        ws[CW_OFF + bid]  = 128.0f * w_width_sh[bid] * cb;
        ws[CHS_OFF + bid] = 128.0f * w_height_sh[bid] * cb;
    }
}

// ---- K2: partial channel-max maps. grid = b(16) x band(16) x cgroup(4) ----
__global__ __launch_bounds__(256) void k_cmax(const float* __restrict__ x,
                                              const float* __restrict__ w_width,
                                              const float* __restrict__ w_height,
                                              float* __restrict__ ws) {
    __shared__ float4 xs4[4 * 18 * 36];      // 4ch x 18rows x 144cols floats
    float* xs = (float*)xs4;
    int bid = blockIdx.x;
    int cg   = bid & 3;
    int band = (bid >> 2) & 15;
    int b    = bid >> 6;
    int r0 = band * 8;
    int tid = threadIdx.x;

    for (int i = tid; i < 4 * 18 * 36; i += 256)
        xs4[i] = make_float4(0.f, 0.f, 0.f, 0.f);

    int lr_o = tid >> 5;             // 0..7 output row within band
    int c0 = (tid & 31) << 2;        // col 0,4,...,124

    float4 mw = make_float4(-INFINITY, -INFINITY, -INFINITY, -INFINITY);
    float4 mh = mw, ms = mw;

    for (int chunk = 0; chunk < 4; chunk++) {
        int ch0 = cg * 16 + chunk * 4;
        __syncthreads();             // prev chunk compute done (and zero-fill)
        for (int j = tid; j < 4 * 576; j += 256) {   // 9 iters
            int i = j / 576;
            int rem = j - i * 576;
            int lr = rem >> 5;
            int c4 = rem & 31;
            int gr = r0 - 5 + lr;
            if (gr >= 0 && gr < 128) {
                float4 v = *(const float4*)(x +
                    ((size_t)((b * 64 + ch0 + i) * 128 + gr)) * 128 + c4 * 4);
                *(float4*)(xs + (i * 18 + lr) * 144 + 8 + c4 * 4) = v;
            }
        }
        __syncthreads();
#pragma unroll
        for (int i = 0; i < 4; i++) {
            int c = ch0 + i;
            float T   = ws[T_OFF + b * 64 + c];
            float cw  = ws[CW_OFF + c];
            float chs = ws[CHS_OFF + c];
            float wk[11], hk[11];
#pragma unroll
            for (int k = 0; k < 11; k++) {
                wk[k] = w_width[c * 11 + k];
                hk[k] = w_height[c * 11 + k];
            }
            float4 w4, h4, s4;
            conv4(xs + (i * 18 + lr_o) * 144 + c0, wk, hk, cw, chs, T, w4, h4, s4);
            mw.x = fmaxf(mw.x, w4.x); mw.y = fmaxf(mw.y, w4.y);
            mw.z = fmaxf(mw.z, w4.z); mw.w = fmaxf(mw.w, w4.w);
            mh.x = fmaxf(mh.x, h4.x); mh.y = fmaxf(mh.y, h4.y);
            mh.z = fmaxf(mh.z, h4.z); mh.w = fmaxf(mh.w, h4.w);
            ms.x = fmaxf(ms.x, s4.x); ms.y = fmaxf(ms.y, s4.y);
            ms.z = fmaxf(ms.z, s4.z); ms.w = fmaxf(ms.w, s4.w);
        }
    }
    int p = b * PLANE + (r0 + lr_o) * 128 + c0;
    *(float4*)(ws + MAP_OFF + (size_t)(cg * 3 + 0) * BP + p) = mw;
    *(float4*)(ws + MAP_OFF + (size_t)(cg * 3 + 1) * BP + p) = mh;
    *(float4*)(ws + MAP_OFF + (size_t)(cg * 3 + 2) * BP + p) = ms;
}

// ---------------- K2b: fold 4 partial groups -> 3 final maps ----------------
__global__ __launch_bounds__(256) void k_combine(float* __restrict__ ws) {
    int id = blockIdx.x * 256 + threadIdx.x;   // 0..196607 float4 slots
    int f = id >> 16;                          // 0..2
    int r = id & 65535;
    float4 m = *(const float4*)(ws + MAP_OFF + (size_t)f * BP + (size_t)r * 4);
#pragma unroll
    for (int g = 1; g < 4; g++) {
        float4 v = *(const float4*)(ws + MAP_OFF + (size_t)(g * 3 + f) * BP + (size_t)r * 4);
        m.x = fmaxf(m.x, v.x); m.y = fmaxf(m.y, v.y);
        m.z = fmaxf(m.z, v.z); m.w = fmaxf(m.w, v.w);
    }
    *(float4*)(ws + FMAP_OFF + (size_t)f * BP + (size_t)r * 4) = m;
}

// -------- K3: recompute fields, mask vs maps, write once; half-plane sums --------
__global__ __launch_bounds__(256) void k_write(
    const float* __restrict__ x,
    const float* __restrict__ w_width, const float* __restrict__ w_height,
    float* __restrict__ ws, float* __restrict__ out) {
    __shared__ float xs[74 * 144];             // 42.6 KB
    __shared__ float red[4 * 5];
    int bid = blockIdx.x;                      // plane*2 + half
    int half = bid & 1;
    int plane = bid >> 1;                      // b*64 + c
    int b = plane >> 6, c = plane & 63;
    int r0 = half * 64;
    int tid = threadIdx.x;

    float4* xs4 = (float4*)xs;
    for (int i = tid; i < 74 * 36; i += 256) xs4[i] = make_float4(0.f, 0.f, 0.f, 0.f);
    __syncthreads();
    const float* xp = x + (size_t)plane * PLANE;
    for (int j = tid; j < 74 * 32; j += 256) {
        int br = j >> 5, c4 = j & 31;
        int gr = r0 - 5 + br;
        if (gr >= 0 && gr < 128)
            *(float4*)&xs[br * 144 + 8 + c4 * 4] =
                *(const float4*)(xp + gr * 128 + c4 * 4);
    }
    float wk[11], hk[11];
#pragma unroll
    for (int k = 0; k < 11; k++) {
        wk[k] = w_width[c * 11 + k];
        hk[k] = w_height[c * 11 + k];
    }
    float T   = ws[T_OFF + plane];
    float cw  = ws[CW_OFF + c];
    float chs = ws[CHS_OFF + c];
    __syncthreads();

    float S = 0.f, Sw = 0.f, Sh = 0.f, Scol = 0.f, Srow = 0.f;
    float* outS = out + (size_t)(b * 192 + c) * PLANE + r0 * 128;
    float* outW = out + (size_t)(b * 192 + 64 + c) * PLANE + r0 * 128;
    float* outH = out + (size_t)(b * 192 + 128 + c) * PLANE + r0 * 128;
    const float* mwp = ws + FMAP_OFF + 0 * (size_t)BP + b * PLANE + r0 * 128;
    const float* mhp = ws + FMAP_OFF + 1 * (size_t)BP + b * PLANE + r0 * 128;
    const float* msp = ws + FMAP_OFF + 2 * (size_t)BP + b * PLANE + r0 * 128;

    for (int g = 0; g < 8; g++) {
        int idx = g * 256 + tid;               // float4 index in half (0..2047)
        int p = idx * 4;
        int y = p >> 7, xc = p & 127;          // y local 0..63
        float4 w4, h4, s4;
        conv4(xs + y * 144 + xc, wk, hk, cw, chs, T, w4, h4, s4);

        float s4sum = s4.x + s4.y + s4.z + s4.w;
        S += s4sum;
        Srow += (float)(r0 + y) * s4sum;
        Sw = fmaf(w4.x, s4.x, Sw); Sw = fmaf(w4.y, s4.y, Sw);
        Sw = fmaf(w4.z, s4.z, Sw); Sw = fmaf(w4.w, s4.w, Sw);
        Sh = fmaf(h4.x, s4.x, Sh); Sh = fmaf(h4.y, s4.y, Sh);
        Sh = fmaf(h4.z, s4.z, Sh); Sh = fmaf(h4.w, s4.w, Sh);
        Scol = fmaf((float)(xc + 0), s4.x, Scol);
        Scol = fmaf((float)(xc + 1), s4.y, Scol);
        Scol = fmaf((float)(xc + 2), s4.z, Scol);
        Scol = fmaf((float)(xc + 3), s4.w, Scol);

        float4 mw = *(const float4*)(mwp + p);
        float4 mh = *(const float4*)(mhp + p);
        float4 ms = *(const float4*)(msp + p);
        float4 o;
        o.x = (s4.x == ms.x) ? s4.x : 0.f;
        o.y = (s4.y == ms.y) ? s4.y : 0.f;
        o.z = (s4.z == ms.z) ? s4.z : 0.f;
        o.w = (s4.w == ms.w) ? s4.w : 0.f;
        ((float4*)outS)[idx] = o;
        o.x = (w4.x == mw.x) ? w4.x : 0.f;
        o.y = (w4.y == mw.y) ? w4.y : 0.f;
        o.z = (w4.z == mw.z) ? w4.z : 0.f;
        o.w = (w4.w == mw.w) ? w4.w : 0.f;
        ((float4*)outW)[idx] = o;
        o.x = (h4.x == mh.x) ? h4.x : 0.f;
        o.y = (h4.y == mh.y) ? h4.y : 0.f;
        o.z = (h4.z == mh.z) ? h4.z : 0.f;
        o.w = (h4.w == mh.w) ? h4.w : 0.f;
        ((float4*)outH)[idx] = o;
    }
#pragma unroll
    for (int off = 32; off; off >>= 1) {
        S    += __shfl_xor(S, off, 64);
        Sw   += __shfl_xor(Sw, off, 64);
        Sh   += __shfl_xor(Sh, off, 64);
        Scol += __shfl_xor(Scol, off, 64);
        Srow += __shfl_xor(Srow, off, 64);
    }
    int wid = tid >> 6, lane = tid & 63;
    if (lane == 0) {
        red[wid * 5 + 0] = S;   red[wid * 5 + 1] = Sw;
        red[wid * 5 + 2] = Sh;  red[wid * 5 + 3] = Scol;
        red[wid * 5 + 4] = Srow;
    }
    __syncthreads();
    if (tid == 0) {
        float a0 = 0, a1 = 0, a2 = 0, a3 = 0, a4 = 0;
#pragma unroll
        for (int w2 = 0; w2 < 4; w2++) {
            a0 += red[w2 * 5 + 0]; a1 += red[w2 * 5 + 1];
            a2 += red[w2 * 5 + 2]; a3 += red[w2 * 5 + 3];
            a4 += red[w2 * 5 + 4];
        }
        int base = SUM_OFF + half * 5120;
        ws[base + 0 * 1024 + plane] = a0;
        ws[base + 1 * 1024 + plane] = a1;
        ws[base + 2 * 1024 + plane] = a2;
        ws[base + 3 * 1024 + plane] = a3;
        ws[base + 4 * 1024 + plane] = a4;
    }
}

// ---------------- K4: bbox rows ----------------
__global__ __launch_bounds__(256) void k_bbox(const float* __restrict__ ws,
                                              float* __restrict__ out) {
    int idx = blockIdx.x * 256 + threadIdx.x;
    if (idx >= 1024) return;
    int b = idx >> 6;
    float S    = ws[SUM_OFF + 0 * 1024 + idx] + ws[SUM_OFF + 5120 + 0 * 1024 + idx];
    float Sw   = ws[SUM_OFF + 1 * 1024 + idx] + ws[SUM_OFF + 5120 + 1 * 1024 + idx];
    float Sh   = ws[SUM_OFF + 2 * 1024 + idx] + ws[SUM_OFF + 5120 + 2 * 1024 + idx];
    float Scol = ws[SUM_OFF + 3 * 1024 + idx] + ws[SUM_OFF + 5120 + 3 * 1024 + idx];
    float Srow = ws[SUM_OFF + 4 * 1024 + idx] + ws[SUM_OFF + 5120 + 4 * 1024 + idx];
    float ps   = ws[PS_OFF + idx];
    float inv = 1.0f / S;
    float wsv = Sw * inv, hsv = Sh * inv;
    float x1 = Scol * inv - 0.5f * wsv;
    float y1 = Srow * inv - 0.5f * hsv;
    float* o = out + OUT0 + (size_t)idx * 6;
    o[0] = (float)b;
    o[1] = x1;
    o[2] = y1;
    o[3] = x1 + wsv;
    o[4] = y1 + hsv;
    o[5] = ps;
}

extern "C" void kernel_launch(void* const* d_in, const int* in_sizes, int n_in,
                              void* d_out, int out_size, void* d_ws, size_t ws_size,
                              hipStream_t stream) {
    const float* x          = (const float*)d_in[0];
    const float* w_bbx      = (const float*)d_in[1];
    const float* w_width    = (const float*)d_in[2];
    const float* w_width_sh = (const float*)d_in[3];
    const float* w_height   = (const float*)d_in[4];
    const float* w_height_sh= (const float*)d_in[5];
    float* out = (float*)d_out;
    float* ws  = (float*)d_ws;

    k_max<<<dim3(1024), dim3(256), 0, stream>>>(x, w_bbx, w_width_sh, w_height_sh, ws);
    k_cmax<<<dim3(1024), dim3(256), 0, stream>>>(x, w_width, w_height, ws);
    k_combine<<<dim3(768), dim3(256), 0, stream>>>(ws);
    k_write<<<dim3(2048), dim3(256), 0, stream>>>(x, w_width, w_height, ws, out);
    k_bbox<<<dim3(4), dim3(256), 0, stream>>>(ws, out);
}